// Round 4
// baseline (255.212 us; speedup 1.0000x reference)
//
#include <hip/hip_runtime.h>
#include <hip/hip_bf16.h>

#define SEQ 1024
#define DIM 128
#define NEG_SLOPE 0.1f

typedef __bf16 bf16x8 __attribute__((ext_vector_type(8)));
typedef float f32x4v __attribute__((ext_vector_type(4)));
typedef unsigned char uchar;

// d_ws layout (bytes):
//   [0, 32M)        maskq[b][i][o']  fp8 (0x38 = 1.0 or 0x00), o' permuted per 64-group
//   [32M, +4M)      ntq[b][d][o']    fp8 e4m3, same o' permutation
//   then Wt, Bt     bf16 [d][k]
#define MASKQ_BYTES ((size_t)32 * 1024 * 1024)
#define NTQ_BYTES   ((size_t)32 * 128 * 1024)

__device__ __forceinline__ unsigned short bfb(float f) {
    __bf16 h = (__bf16)f;
    return __builtin_bit_cast(unsigned short, h);
}

// o' permutation within each 64-group: stored position p = quad*16 + half*8 + j
// holds original o = half*32 + quad*8 + j.  One dwordx4 at p=quad*16 then feeds
// MFMA#half with k=quad*8+j for half=0 (low 8B) and half=1 (high 8B).

// f32 -> e4m3fn RNE (values here are |f| < 16, no saturation concerns)
__device__ __forceinline__ uchar f32_to_e4m3(float f) {
#if __has_builtin(__builtin_amdgcn_cvt_pk_fp8_f32)
    int r = __builtin_amdgcn_cvt_pk_fp8_f32(f, f, 0, false);
    return (uchar)(r & 0xff);
#else
    unsigned u = __builtin_bit_cast(unsigned, f);
    unsigned s = (u >> 24) & 0x80;
    int e = (u >> 23) & 0xff;
    unsigned m = u & 0x7fffff;
    int te = e - 120;
    if (te >= 1) {
        unsigned keep = m >> 20, rest = m & 0xfffff;
        keep += (rest > 0x80000u) || (rest == 0x80000u && (keep & 1));
        if (keep == 8) { keep = 0; ++te; }
        if (te > 15) return (uchar)(s | 0x7e);
        return (uchar)(s | (te << 3) | keep);
    }
    float af = f < 0 ? -f : f;
    int q = (int)(af * 512.0f + 0.5f);
    if (q > 7) q = 7;
    return (uchar)(s | q);
#endif
}

// ---- kernel 1: adj[b][o][i] int32 -> maskq[b][i][o'] fp8, tile 64o x 64i ----
// grid = 32 * 16 * 16 = 8192, block 256. Pure streaming: 16 KB in, 4 KB out per block.
__global__ __launch_bounds__(256)
void transpose_adj(const int* __restrict__ adj, uchar* __restrict__ mq)
{
    __shared__ uchar lds[64][72];   // [i][o], 72 stride keeps 8B-aligned rows
    const int b  = blockIdx.x >> 8;
    const int ot = (blockIdx.x >> 4) & 15;
    const int it = blockIdx.x & 15;
    const int o0 = ot << 6, i0 = it << 6;
    const int t  = threadIdx.x;

    const int r0 = (t >> 4) << 2;   // o row group
    const int c0 = (t & 15) << 2;   // i col group
    const int* pa = adj + ((size_t)(b * SEQ + o0 + r0)) * SEQ + i0 + c0;
    int4 A[4];
    #pragma unroll
    for (int r = 0; r < 4; ++r) A[r] = *(const int4*)(pa + (size_t)r * SEQ);

    #pragma unroll
    for (int c = 0; c < 4; ++c) {
        unsigned w = 0;
        w |= (((const int*)&A[0])[c] != 0 ? 0x38u : 0u);
        w |= (((const int*)&A[1])[c] != 0 ? 0x38u : 0u) << 8;
        w |= (((const int*)&A[2])[c] != 0 ? 0x38u : 0u) << 16;
        w |= (((const int*)&A[3])[c] != 0 ? 0x38u : 0u) << 24;
        *(unsigned*)&lds[c0 + c][r0] = w;
    }
    __syncthreads();

    const int i_loc = t >> 2;
    const int quad  = t & 3;
    const uint2 lo = *(const uint2*)&lds[i_loc][quad * 8];        // half 0: o = quad*8+j
    const uint2 hi = *(const uint2*)&lds[i_loc][32 + quad * 8];   // half 1: o = 32+quad*8+j
    uint4 outv; outv.x = lo.x; outv.y = lo.y; outv.z = hi.x; outv.w = hi.y;
    *(uint4*)(mq + ((size_t)(b * SEQ + i0 + i_loc)) * SEQ + o0 + quad * 16) = outv;
}

// ---- kernel 2: nodes[b][o][d] f32 -> ntq[b][d][o'] fp8, tile 64o x 32d ----
// grid = 32 * 16 * 4 = 2048, block 256
__global__ __launch_bounds__(256)
void transpose_nodes(const float* __restrict__ nodes, uchar* __restrict__ nq)
{
    __shared__ float lds[64][33];
    const int b  = blockIdx.x >> 6;
    const int ot = (blockIdx.x >> 2) & 15;
    const int dt = blockIdx.x & 3;
    const int o0 = ot << 6, d0 = dt << 5;
    const int t  = threadIdx.x;

    const float* src = nodes + ((size_t)(b * SEQ + o0)) * DIM + d0;
    #pragma unroll
    for (int p = 0; p < 8; ++p) {
        const int o = (t >> 5) + p * 8;
        const int d = t & 31;
        lds[o][d] = src[(size_t)o * DIM + d];
    }
    __syncthreads();

    const int d_loc = t >> 3;                 // 0..31
    const int p0    = (t & 7) * 8;            // byte offset in 64-group
    const int quad  = (t & 7) >> 1;
    const int half  = t & 1;
    const int ob    = half * 32 + quad * 8;   // original o base for these 8 bytes
    union { uchar b[8]; uint2 u; } pk;
    #pragma unroll
    for (int j = 0; j < 8; ++j) pk.b[j] = f32_to_e4m3(lds[ob + j][d_loc]);
    *(uint2*)(nq + ((size_t)(b * DIM + d0 + d_loc)) * SEQ + o0 + p0) = pk.u;
}

// ---- kernel 3: W,B [k][d] f32 -> Wt,Bt [d][k] bf16 ----
__global__ __launch_bounds__(256)
void transpose_wb(const float* __restrict__ W, const float* __restrict__ Bm,
                  unsigned short* __restrict__ wt, unsigned short* __restrict__ bt)
{
    const int which = blockIdx.x & 1;
    const int slice = blockIdx.x >> 1;
    const float* in = which ? Bm : W;
    unsigned short* out = which ? bt : wt;
    const int base = slice * 1024;
    #pragma unroll
    for (int r = 0; r < 4; ++r) {
        const int idx = base + r * 256 + threadIdx.x;
        const int d = idx >> 7, k = idx & 127;
        out[idx] = bfb(in[k * DIM + d]);
    }
}

__device__ __forceinline__ long mk64(unsigned lo, unsigned hi) {
    return (long)(((unsigned long long)hi << 32) | lo);
}

// ---- main kernel: barrier-free fp8 K-loop + bf16 epilogue ----
// tile 64(i) x 128(d), grid 512 = 32 batch x 16 mtile, block 256 (2x2 waves)
__global__ __launch_bounds__(256, 2)
void gcn_main(const float* __restrict__ nodes,
              const uchar* __restrict__ mq,
              const uchar* __restrict__ nq,
              const unsigned short* __restrict__ wt,
              const unsigned short* __restrict__ bt,
              float* __restrict__ out)
{
    __shared__ unsigned short pooled[64][136];

    const int bid   = blockIdx.x;
    const int xcd   = bid & 7;
    const int slot  = bid >> 3;
    const int batch = ((slot >> 4) << 3) | xcd;
    const int mtile = slot & 15;
    const int i0    = mtile << 6;

    const int tid  = threadIdx.x;
    const int wave = tid >> 6;
    const int lane = tid & 63;
    const int wm   = wave >> 1;
    const int wn   = wave & 1;
    const int lrow = lane & 15;
    const int quad = lane >> 4;

    const uchar* __restrict__ mq_b = mq + (size_t)batch * SEQ * SEQ;
    const uchar* __restrict__ nq_b = nq + (size_t)batch * DIM * SEQ;
    const float* __restrict__ nodes_b = nodes + (size_t)batch * SEQ * DIM;

    f32x4v acc[2][4] = {};
    f32x4v acc_cnt[2] = {};
    const long ones = 0x3838383838383838L;   // 8x e4m3 1.0

    const uchar* pa0 = mq_b + (size_t)(i0 + wm * 32 + lrow) * SEQ + quad * 16;
    const uchar* pb0 = nq_b + (size_t)(wn * 64 + lrow) * SEQ + quad * 16;

    // K-loop: NO LDS, NO barriers. 6 dwordx4 loads + 20 MFMA per 64-o chunk.
    #pragma unroll 4
    for (int n = 0; n < 16; ++n) {
        const int off = n * 64;
        uint4 a4[2], b4[4];
        #pragma unroll
        for (int mf = 0; mf < 2; ++mf)
            a4[mf] = *(const uint4*)(pa0 + (size_t)mf * 16 * SEQ + off);
        #pragma unroll
        for (int nf = 0; nf < 4; ++nf)
            b4[nf] = *(const uint4*)(pb0 + (size_t)nf * 16 * SEQ + off);
        #pragma unroll
        for (int half = 0; half < 2; ++half) {
            long a64[2], b64[4];
            #pragma unroll
            for (int mf = 0; mf < 2; ++mf)
                a64[mf] = half ? mk64(a4[mf].z, a4[mf].w) : mk64(a4[mf].x, a4[mf].y);
            #pragma unroll
            for (int nf = 0; nf < 4; ++nf)
                b64[nf] = half ? mk64(b4[nf].z, b4[nf].w) : mk64(b4[nf].x, b4[nf].y);
            #pragma unroll
            for (int mf = 0; mf < 2; ++mf) {
                #pragma unroll
                for (int nf = 0; nf < 4; ++nf)
                    acc[mf][nf] = __builtin_amdgcn_mfma_f32_16x16x32_fp8_fp8(
                        a64[mf], b64[nf], acc[mf][nf], 0, 0, 0);
                acc_cnt[mf] = __builtin_amdgcn_mfma_f32_16x16x32_fp8_fp8(
                    a64[mf], ones, acc_cnt[mf], 0, 0, 0);
            }
        }
    }

    // poolsum -> pooled (divide by exact MFMA in-degree), C-layout -> A-layout via LDS
    #pragma unroll
    for (int mf = 0; mf < 2; ++mf) {
        #pragma unroll
        for (int r = 0; r < 4; ++r) {
            const int row = wm * 32 + mf * 16 + quad * 4 + r;
            const float cnt = acc_cnt[mf][r];
            const float inv = (cnt > 0.5f) ? 1.0f / cnt : 0.0f;
            #pragma unroll
            for (int nf = 0; nf < 4; ++nf) {
                const int col = wn * 64 + nf * 16 + lrow;
                pooled[row][col] = bfb(acc[mf][nf][r] * inv);
            }
        }
    }
    __syncthreads();

    f32x4v acc2[2][4] = {};
    const int d_b0 = wn * 64 + lrow;

    // pooled @ W + nodes @ B  (K=128, bf16)
    #pragma unroll
    for (int ks = 0; ks < 4; ++ks) {
        const int k0 = ks * 32 + quad * 8;
        bf16x8 av[2], av2[2], bw[4], bb[4];
        #pragma unroll
        for (int mf = 0; mf < 2; ++mf) {
            av[mf] = *(const bf16x8*)&pooled[wm * 32 + mf * 16 + lrow][k0];
            const float* p = nodes_b + (size_t)(i0 + wm * 32 + mf * 16 + lrow) * DIM + k0;
            const float4 f1 = *(const float4*)p;
            const float4 f2 = *(const float4*)(p + 4);
            av2[mf][0] = (__bf16)f1.x; av2[mf][1] = (__bf16)f1.y;
            av2[mf][2] = (__bf16)f1.z; av2[mf][3] = (__bf16)f1.w;
            av2[mf][4] = (__bf16)f2.x; av2[mf][5] = (__bf16)f2.y;
            av2[mf][6] = (__bf16)f2.z; av2[mf][7] = (__bf16)f2.w;
        }
        #pragma unroll
        for (int nf = 0; nf < 4; ++nf) {
            bw[nf] = *(const bf16x8*)(wt + (size_t)(d_b0 + nf * 16) * DIM + k0);
            bb[nf] = *(const bf16x8*)(bt + (size_t)(d_b0 + nf * 16) * DIM + k0);
        }
        #pragma unroll
        for (int mf = 0; mf < 2; ++mf)
            #pragma unroll
            for (int nf = 0; nf < 4; ++nf) {
                acc2[mf][nf] = __builtin_amdgcn_mfma_f32_16x16x32_bf16(av[mf],  bw[nf], acc2[mf][nf], 0, 0, 0);
                acc2[mf][nf] = __builtin_amdgcn_mfma_f32_16x16x32_bf16(av2[mf], bb[nf], acc2[mf][nf], 0, 0, 0);
            }
    }

    float* out_b = out + (size_t)batch * SEQ * DIM;
    #pragma unroll
    for (int mf = 0; mf < 2; ++mf) {
        #pragma unroll
        for (int nf = 0; nf < 4; ++nf) {
            const int col = wn * 64 + nf * 16 + lrow;
            #pragma unroll
            for (int r = 0; r < 4; ++r) {
                const int row = i0 + wm * 32 + mf * 16 + quad * 4 + r;
                const float x = acc2[mf][nf][r];
                out_b[(size_t)row * DIM + col] = (x > 0.0f) ? x : NEG_SLOPE * x;
            }
        }
    }
}

extern "C" void kernel_launch(void* const* d_in, const int* in_sizes, int n_in,
                              void* d_out, int out_size, void* d_ws, size_t ws_size,
                              hipStream_t stream) {
    const float* nodes = (const float*)d_in[0];
    const int*   adj   = (const int*)d_in[1];
    const float* W     = (const float*)d_in[2];
    const float* Bm    = (const float*)d_in[3];
    float*       out   = (float*)d_out;

    uchar* mq = (uchar*)d_ws;
    uchar* nq = mq + MASKQ_BYTES;
    unsigned short* wt = (unsigned short*)(nq + NTQ_BYTES);
    unsigned short* bt = wt + 16384;

    transpose_adj  <<<dim3(8192), dim3(256), 0, stream>>>(adj, mq);
    transpose_nodes<<<dim3(2048), dim3(256), 0, stream>>>(nodes, nq);
    transpose_wb   <<<dim3(32),   dim3(256), 0, stream>>>(W, Bm, wt, bt);
    gcn_main       <<<dim3(512),  dim3(256), 0, stream>>>(nodes, mq, nq, wt, bt, out);
}

// Round 5
// 248.253 us; speedup vs baseline: 1.0280x; 1.0280x over previous
//
#include <hip/hip_runtime.h>
#include <hip/hip_bf16.h>

#define SEQ 1024
#define DIM 128
#define NEG_SLOPE 0.1f

typedef __bf16 bf16x8 __attribute__((ext_vector_type(8)));
typedef float f32x4v __attribute__((ext_vector_type(4)));
typedef unsigned char uchar;

// d_ws layout: ntq fp8 [b][d][o] (4 MB), then Wt, Bt bf16 [d][k]
#define NTQ_BYTES ((size_t)32 * 128 * 1024)

__device__ __forceinline__ unsigned short bfb(float f) {
    __bf16 h = (__bf16)f;
    return __builtin_bit_cast(unsigned short, h);
}

// f32 -> e4m3fn RNE
__device__ __forceinline__ uchar f32_to_e4m3(float f) {
#if __has_builtin(__builtin_amdgcn_cvt_pk_fp8_f32)
    int r = __builtin_amdgcn_cvt_pk_fp8_f32(f, f, 0, false);
    return (uchar)(r & 0xff);
#else
    unsigned u = __builtin_bit_cast(unsigned, f);
    unsigned s = (u >> 24) & 0x80;
    int e = (u >> 23) & 0xff;
    unsigned m = u & 0x7fffff;
    int te = e - 120;
    if (te >= 1) {
        unsigned keep = m >> 20, rest = m & 0xfffff;
        keep += (rest > 0x80000u) || (rest == 0x80000u && (keep & 1));
        if (keep == 8) { keep = 0; ++te; }
        if (te > 15) return (uchar)(s | 0x7e);
        return (uchar)(s | (te << 3) | keep);
    }
    float af = f < 0 ? -f : f;
    int q = (int)(af * 512.0f + 0.5f);
    if (q > 7) q = 7;
    return (uchar)(s | q);
#endif
}

__device__ __forceinline__ long mk64(unsigned lo, unsigned hi) {
    return (long)(((unsigned long long)hi << 32) | lo);
}

// ---- pre-kernel 1: nodes[b][o][d] f32 -> ntq[b][d][o] fp8 e4m3 (natural o order) ----
// grid = 32 * 16 * 4 = 2048, block 256
__global__ __launch_bounds__(256)
void transpose_nodes(const float* __restrict__ nodes, uchar* __restrict__ nq)
{
    __shared__ float lds[64][33];
    const int b  = blockIdx.x >> 6;
    const int ot = (blockIdx.x >> 2) & 15;
    const int dt = blockIdx.x & 3;
    const int o0 = ot << 6, d0 = dt << 5;
    const int t  = threadIdx.x;

    const float* src = nodes + ((size_t)(b * SEQ + o0)) * DIM + d0;
    #pragma unroll
    for (int p = 0; p < 8; ++p) {
        const int o = (t >> 5) + p * 8;
        const int d = t & 31;
        lds[o][d] = src[(size_t)o * DIM + d];
    }
    __syncthreads();

    const int d_loc = t >> 3;        // 0..31
    const int p0    = (t & 7) * 8;   // o offset
    union { uchar b[8]; uint2 u; } pk;
    #pragma unroll
    for (int j = 0; j < 8; ++j) pk.b[j] = f32_to_e4m3(lds[p0 + j][d_loc]);
    *(uint2*)(nq + ((size_t)(b * DIM + d0 + d_loc)) * SEQ + o0 + p0) = pk.u;
}

// ---- pre-kernel 2: W,B [k][d] f32 -> Wt,Bt [d][k] bf16 ----
__global__ __launch_bounds__(256)
void transpose_wb(const float* __restrict__ W, const float* __restrict__ Bm,
                  unsigned short* __restrict__ wt, unsigned short* __restrict__ bt)
{
    const int which = blockIdx.x & 1;
    const int slice = blockIdx.x >> 1;
    const float* in = which ? Bm : W;
    unsigned short* out = which ? bt : wt;
    const int base = slice * 1024;
    #pragma unroll
    for (int r = 0; r < 4; ++r) {
        const int idx = base + r * 256 + threadIdx.x;
        const int d = idx >> 7, k = idx & 127;
        out[idx] = bfb(in[k * DIM + d]);
    }
}

// ---- main fused kernel ----
// tile 32(i) x 128(d), grid 1024 = 32 batch x 32 itile -> 4 blocks/CU.
// K-loop: adj streamed HBM->regs->LDS fp8 (8 KB/chunk, 1 barrier, dbuf),
// nodes fp8 read straight from global (L2-hot), both pipelined 1 chunk ahead.
__global__ __launch_bounds__(256, 4)
void gcn_main(const float* __restrict__ nodes,
              const int* __restrict__ adj,
              const uchar* __restrict__ nq,
              const unsigned short* __restrict__ wt,
              const unsigned short* __restrict__ bt,
              float* __restrict__ out)
{
    __shared__ __align__(16) uchar mask_t[2][32][80];   // [buf][i][o] fp8, stride 80B
    __shared__ unsigned short pooled[32][136];          // [i][d] bf16 bits

    const int bid   = blockIdx.x;
    const int xcd   = bid & 7;
    const int slot  = bid >> 3;
    const int batch = ((slot >> 5) << 3) | xcd;   // [0,32)
    const int itile = slot & 31;
    const int i0    = itile << 5;

    const int tid  = threadIdx.x;
    const int wave = tid >> 6;
    const int lane = tid & 63;
    const int wh   = wave >> 1;   // i-half (16 rows)
    const int wn   = wave & 1;    // d-half (64 cols)
    const int lrow = lane & 15;
    const int quad = lane >> 4;

    const int*   __restrict__ adj_b   = adj   + (size_t)batch * SEQ * SEQ;
    const uchar* __restrict__ nq_b    = nq    + (size_t)batch * DIM * SEQ;
    const float* __restrict__ nodes_b = nodes + (size_t)batch * SEQ * DIM;

    // adj staging: thread covers 4 o-rows x 2 i-cols (int2), per-row 128B coalesced
    const int ig = tid & 15;     // i pair base = ig*2
    const int og = tid >> 4;     // o group of 4 = og*4

    f32x4v acc[4] = {};
    f32x4v acc_cnt = {};
    const long ones = 0x3838383838383838L;   // 8x e4m3 1.0

    int2 A[4];
    auto load_adj = [&](int oc) {
        const int* pa = adj_b + (size_t)(oc + og * 4) * SEQ + i0 + ig * 2;
        #pragma unroll
        for (int rr = 0; rr < 4; ++rr) A[rr] = *(const int2*)(pa + (size_t)rr * SEQ);
    };
    uint4 Bv[4];
    const uchar* pb0 = nq_b + (size_t)(wn * 64 + lrow) * SEQ + quad * 16;
    auto load_B = [&](int off) {
        #pragma unroll
        for (int nf = 0; nf < 4; ++nf)
            Bv[nf] = *(const uint4*)(pb0 + (size_t)nf * 16 * SEQ + off);
    };

    load_adj(0);
    load_B(0);

    for (int n = 0; n < 16; ++n) {
        const int buf = n & 1;
        // stage chunk n's adj (4x1 in-reg transpose -> two u32 LDS writes)
        unsigned w0 = 0, w1 = 0;
        #pragma unroll
        for (int rr = 0; rr < 4; ++rr) {
            w0 |= (A[rr].x != 0 ? 0x38u : 0u) << (8 * rr);
            w1 |= (A[rr].y != 0 ? 0x38u : 0u) << (8 * rr);
        }
        *(unsigned*)&mask_t[buf][ig * 2][og * 4]     = w0;
        *(unsigned*)&mask_t[buf][ig * 2 + 1][og * 4] = w1;
        __syncthreads();

        uint4 Bc[4];
        #pragma unroll
        for (int nf = 0; nf < 4; ++nf) Bc[nf] = Bv[nf];
        if (n < 15) {                     // prefetch chunk n+1 (full-iter latency cover)
            load_adj((n + 1) * 64);
            load_B((n + 1) * 64);
        }

        const uint4 a4 = *(const uint4*)&mask_t[buf][wh * 16 + lrow][quad * 16];
        #pragma unroll
        for (int half = 0; half < 2; ++half) {
            const long a64 = half ? mk64(a4.z, a4.w) : mk64(a4.x, a4.y);
            #pragma unroll
            for (int nf = 0; nf < 4; ++nf) {
                const long b64 = half ? mk64(Bc[nf].z, Bc[nf].w) : mk64(Bc[nf].x, Bc[nf].y);
                acc[nf] = __builtin_amdgcn_mfma_f32_16x16x32_fp8_fp8(a64, b64, acc[nf], 0, 0, 0);
            }
            acc_cnt = __builtin_amdgcn_mfma_f32_16x16x32_fp8_fp8(a64, ones, acc_cnt, 0, 0, 0);
        }
    }

    // poolsum -> pooled (divide by exact MFMA in-degree), C-layout -> A-layout via LDS
    #pragma unroll
    for (int r = 0; r < 4; ++r) {
        const int row = wh * 16 + quad * 4 + r;
        const float cnt = acc_cnt[r];
        const float inv = (cnt > 0.5f) ? 1.0f / cnt : 0.0f;
        #pragma unroll
        for (int nf = 0; nf < 4; ++nf) {
            const int col = wn * 64 + nf * 16 + lrow;
            pooled[row][col] = bfb(acc[nf][r] * inv);
        }
    }
    __syncthreads();

    f32x4v acc2[4] = {};
    const int d_b0 = wn * 64 + lrow;

    // pooled @ W + nodes @ B  (K=128, bf16)
    #pragma unroll
    for (int ks = 0; ks < 4; ++ks) {
        const int k0 = ks * 32 + quad * 8;
        bf16x8 av, av2, bw[4], bb[4];
        av = *(const bf16x8*)&pooled[wh * 16 + lrow][k0];
        {
            const float* p = nodes_b + (size_t)(i0 + wh * 16 + lrow) * DIM + k0;
            const float4 f1 = *(const float4*)p;
            const float4 f2 = *(const float4*)(p + 4);
            av2[0] = (__bf16)f1.x; av2[1] = (__bf16)f1.y;
            av2[2] = (__bf16)f1.z; av2[3] = (__bf16)f1.w;
            av2[4] = (__bf16)f2.x; av2[5] = (__bf16)f2.y;
            av2[6] = (__bf16)f2.z; av2[7] = (__bf16)f2.w;
        }
        #pragma unroll
        for (int nf = 0; nf < 4; ++nf) {
            bw[nf] = *(const bf16x8*)(wt + (size_t)(d_b0 + nf * 16) * DIM + k0);
            bb[nf] = *(const bf16x8*)(bt + (size_t)(d_b0 + nf * 16) * DIM + k0);
        }
        #pragma unroll
        for (int nf = 0; nf < 4; ++nf) {
            acc2[nf] = __builtin_amdgcn_mfma_f32_16x16x32_bf16(av,  bw[nf], acc2[nf], 0, 0, 0);
            acc2[nf] = __builtin_amdgcn_mfma_f32_16x16x32_bf16(av2, bb[nf], acc2[nf], 0, 0, 0);
        }
    }

    // leaky-relu + store
    float* out_b = out + (size_t)batch * SEQ * DIM;
    #pragma unroll
    for (int nf = 0; nf < 4; ++nf) {
        const int col = wn * 64 + nf * 16 + lrow;
        #pragma unroll
        for (int r = 0; r < 4; ++r) {
            const int row = i0 + wh * 16 + quad * 4 + r;
            const float x = acc2[nf][r];
            out_b[(size_t)row * DIM + col] = (x > 0.0f) ? x : NEG_SLOPE * x;
        }
    }
}

extern "C" void kernel_launch(void* const* d_in, const int* in_sizes, int n_in,
                              void* d_out, int out_size, void* d_ws, size_t ws_size,
                              hipStream_t stream) {
    const float* nodes = (const float*)d_in[0];
    const int*   adj   = (const int*)d_in[1];
    const float* W     = (const float*)d_in[2];
    const float* Bm    = (const float*)d_in[3];
    float*       out   = (float*)d_out;

    uchar* nq = (uchar*)d_ws;
    unsigned short* wt = (unsigned short*)(nq + NTQ_BYTES);
    unsigned short* bt = wt + 16384;

    transpose_nodes<<<dim3(2048), dim3(256), 0, stream>>>(nodes, nq);
    transpose_wb   <<<dim3(32),   dim3(256), 0, stream>>>(W, Bm, wt, bt);
    gcn_main       <<<dim3(1024), dim3(256), 0, stream>>>(nodes, adj, nq, wt, bt, out);
}